// Round 5
// baseline (329.372 us; speedup 1.0000x reference)
//
#include <hip/hip_runtime.h>

#define IMG 28
#define NPIX (IMG * IMG)           // 784
#define CENTER 14
#define SROW 36                    // LDS row pitch in floats (9 f4; odd f4 pitch
                                   // rotates banks by 4 per row -> <=2-way, free)
#define SPAD 4                     // front pad so (row0, col-1) stays in-bounds
#define SFLOATS (30 * SROW + SPAD) // 1084 floats = 4336 B per wave
#define SF4 (SFLOATS / 4)          // 271 f4

typedef float f4 __attribute__((ext_vector_type(4)));

// out = x everywhere except the annulus {(t-1)^2 < d2 <= t^2} (t=0: center
// pixel only), where out = x + conv3x3(x) + b.  Cross-correlation, SAME pad.
//
// Structure: 1 wave = 1 image, 4 images / 256-thread block, no barriers
// (each wave only touches its own LDS segment; intra-wave lgkmcnt orders).
//
// This round:
//  - Shared-tap conv: the 3x3 taps of 4 consecutive pixels overlap; 14
//    ds_read_b32 (6 top + 6 bottom + 2 middle-edge; middle centers come from
//    the in-register v[kk]) replace 36, and the 4 per-element exec-mask
//    branches are replaced by unconditional FMA chains + per-element
//    cndmask select. FMA order per element is unchanged -> bit-identical.
//  - SROW 32 -> 36: row stride 32 made all same-column lanes (rows 7 lanes
//    apart) hit one bank (~9-way). 36 rotates banks by 4/row (<=2-way, free).
//  - Halo: zero the whole segment with 5 stride-1 ds_write_b128, then stage
//    (same-wave LDS ops execute in program order).
__global__ __launch_bounds__(256, 4) void SuperResolution_89876485636254_kernel(
    const float* __restrict__ x,
    const int*   __restrict__ t,
    const float* __restrict__ Wk,
    const float* __restrict__ bias,
    float*       __restrict__ out)
{
    __shared__ float s2[4][SFLOATS];

    const int wave = threadIdx.x >> 6;
    const int lane = threadIdx.x & 63;
    const int img  = blockIdx.x * 4 + wave;

    const f4* __restrict__ xin4 = (const f4*)(x + (size_t)img * NPIX);
    f4*       __restrict__ out4 = (f4*)(out + (size_t)img * NPIX);

    // wave-uniform metadata first
    const int rt = t[img];

    // issue all global loads up front (touch-once stream)
    f4 v[4];
    v[0] = __builtin_nontemporal_load(xin4 + lane);
    v[1] = __builtin_nontemporal_load(xin4 + lane + 64);
    v[2] = __builtin_nontemporal_load(xin4 + lane + 128);
    if (lane < 4) v[3] = __builtin_nontemporal_load(xin4 + lane + 192);

    const int r2  = rt * rt;
    const int ir2 = (rt >= 1) ? (rt - 1) * (rt - 1) : -1;  // inner radius^2
    const float bb = bias[0];
    float w[9];
    #pragma unroll
    for (int i = 0; i < 9; ++i) w[i] = Wk[i];

    f4* sw4 = (f4*)s2[wave];

    // zero-fill the whole segment (271 f4): 5 stride-1 b128 writes
    {
        const f4 z = {0.f, 0.f, 0.f, 0.f};
        sw4[lane]       = z;
        sw4[lane + 64]  = z;
        sw4[lane + 128] = z;
        sw4[lane + 192] = z;
        if (lane < SF4 - 256) sw4[lane + 256] = z;   // 256..270
    }

    // stage image: data row i, f4-col q at f4 index 10 + 9*i + q
    #pragma unroll
    for (int kk = 0; kk < 4; ++kk) {
        if (kk < 3 || lane < 4) {
            const int k = lane + kk * 64;
            const int i = k / 7;
            sw4[10 + 9 * i + (k - 7 * i)] = v[kk];
        }
    }

    const float* __restrict__ simg = s2[wave];

    #pragma unroll
    for (int kk = 0; kk < 4; ++kk) {
        if (kk < 3 || lane < 4) {
            const int k = lane + kk * 64;
            f4 r = v[kk];
            const int i   = k / 7;
            const int j0  = 4 * (k - 7 * i);
            const int di  = i - CENTER;
            const int di2 = di * di;
            // row-band early-out: di2 > r2 => whole f4 is a pure copy
            if (di2 <= r2) {
                // shared taps: top/bottom rows cols j0-1..j0+4, middle edges
                const float* rowT = simg + SPAD +  i      * SROW + (j0 - 1);
                const float* rowM = simg + SPAD + (i + 1) * SROW + (j0 - 1);
                const float* rowB = simg + SPAD + (i + 2) * SROW + (j0 - 1);
                const float T0 = rowT[0], T1 = rowT[1], T2 = rowT[2],
                            T3 = rowT[3], T4 = rowT[4], T5 = rowT[5];
                const float B0 = rowB[0], B1 = rowB[1], B2 = rowB[2],
                            B3 = rowB[3], B4 = rowB[4], B5 = rowB[5];
                const float M0 = rowM[0], M5 = rowM[5];
                const float m1 = r.x, m2 = r.y, m3 = r.z, m4 = r.w;

                // per-element accs, FMA order identical to the 3x3 loop
                float a0 = bb, a1 = bb, a2 = bb, a3 = bb;
                a0 += w[0]*T0; a0 += w[1]*T1; a0 += w[2]*T2;
                a0 += w[3]*M0; a0 += w[4]*m1; a0 += w[5]*m2;
                a0 += w[6]*B0; a0 += w[7]*B1; a0 += w[8]*B2;

                a1 += w[0]*T1; a1 += w[1]*T2; a1 += w[2]*T3;
                a1 += w[3]*m1; a1 += w[4]*m2; a1 += w[5]*m3;
                a1 += w[6]*B1; a1 += w[7]*B2; a1 += w[8]*B3;

                a2 += w[0]*T2; a2 += w[1]*T3; a2 += w[2]*T4;
                a2 += w[3]*m2; a2 += w[4]*m3; a2 += w[5]*m4;
                a2 += w[6]*B2; a2 += w[7]*B3; a2 += w[8]*B4;

                a3 += w[0]*T3; a3 += w[1]*T4; a3 += w[2]*T5;
                a3 += w[3]*m3; a3 += w[4]*m4; a3 += w[5]*M5;
                a3 += w[6]*B3; a3 += w[7]*B4; a3 += w[8]*B5;

                const int dj0 = j0 - CENTER;
                const int d20 = di2 + dj0 * dj0;
                const int d21 = di2 + (dj0 + 1) * (dj0 + 1);
                const int d22 = di2 + (dj0 + 2) * (dj0 + 2);
                const int d23 = di2 + (dj0 + 3) * (dj0 + 3);
                r.x = (d20 <= r2 && d20 > ir2) ? r.x + a0 : r.x;
                r.y = (d21 <= r2 && d21 > ir2) ? r.y + a1 : r.y;
                r.z = (d22 <= r2 && d22 > ir2) ? r.z + a2 : r.z;
                r.w = (d23 <= r2 && d23 > ir2) ? r.w + a3 : r.w;
            }
            __builtin_nontemporal_store(r, out4 + k);  // out is touch-once
        }
    }
}

extern "C" void kernel_launch(void* const* d_in, const int* in_sizes, int n_in,
                              void* d_out, int out_size, void* d_ws, size_t ws_size,
                              hipStream_t stream) {
    const float* x    = (const float*)d_in[0];
    const int*   t    = (const int*)d_in[1];
    const float* Wk   = (const float*)d_in[2];
    const float* bias = (const float*)d_in[3];
    float*       out  = (float*)d_out;

    const int B = in_sizes[0] / NPIX;        // 65536
    const int blocks = B / 4;                // 4 images per 256-thread block

    SuperResolution_89876485636254_kernel<<<blocks, 256, 0, stream>>>(
        x, t, Wk, bias, out);
}